// Round 2
// baseline (1063.133 us; speedup 1.0000x reference)
//
#include <hip/hip_runtime.h>
#include <math.h>

// Problem constants: B=4, NF=64, H=W=128, K=9
// d_in order: nbr, ref, w1, b1, w2, b2, w3, b3, w_off, b_off, w_dcn, b_dcn
// d_out: feat [4,64,128,128] | offset [4,18,128,128] | mask [4,9,128,128]

// ---------------- weight transpose: w[oc][c][k] -> wT[(c*9+k)*OC + oc]
__global__ void wtrans_kernel(const float* __restrict__ in, float* __restrict__ out,
                              int OC, int IC) {
  int i = blockIdx.x * 256 + threadIdx.x;
  int total = OC * IC * 9;
  if (i >= total) return;
  int ic9 = IC * 9;
  int oc = i / ic9;
  int r = i - oc * ic9;
  int c = r / 9;
  int k = r - c * 9;
  out[(c * 9 + k) * OC + oc] = in[i];
}

// ---------------- NCHW -> NHWC transpose: (B,64,128,128) -> (B,128,128,64)
__global__ __launch_bounds__(256) void transpose_nhwc_kernel(const float* __restrict__ in,
                                                             float* __restrict__ out) {
  __shared__ float t[64 * 129];
  int bz = blockIdx.x;            // b*128 + y
  int b = bz >> 7, y = bz & 127;
  int tid = threadIdx.x;
  for (int l = tid; l < 8192; l += 256) {
    int c = l >> 7, x = l & 127;
    t[c * 129 + x] = in[(((b << 6) + c) << 14) + (y << 7) + x];
  }
  __syncthreads();
  for (int l = tid; l < 8192; l += 256) {
    int x = l >> 6, c = l & 63;   // lanes: consecutive c -> coalesced write, 2-way LDS alias (free)
    out[(((((b << 7) + y) << 7) + x) << 6) + c] = t[c * 129 + x];
  }
}

// ---------------- direct conv3x3 + bias + lrelu. wT layout [c][k][64].
// Tile 32x8 px, CC=4 channel chunks staged in LDS (halo 34x10, stride 34).
// S: out-channel split (grid.z = B*S), each block computes 64/S channels.
template <int CIN, bool CONCAT, int S>
__global__ __launch_bounds__(256) void conv3x3_lrelu_kernel(
    const float* __restrict__ in0, const float* __restrict__ in1,
    const float* __restrict__ wT, const float* __restrict__ bias,
    float* __restrict__ out) {
  constexpr int OCB = 64 / S;
  constexpr int CC = 4;
  __shared__ float s_in[CC * 340];
  int tid = threadIdx.x;
  int tx = tid & 31, ty = tid >> 5;
  int w0 = blockIdx.x * 32, h0 = blockIdx.y * 8;
  int bz = blockIdx.z;
  int b = bz / S, s = bz % S;
  int h = h0 + ty, w = w0 + tx;

  float acc[OCB];
#pragma unroll
  for (int i = 0; i < OCB; ++i) acc[i] = 0.f;

  for (int c0 = 0; c0 < CIN; c0 += CC) {
    __syncthreads();
    for (int l = tid; l < CC * 340; l += 256) {
      int cc = l / 340;
      int rem = l - cc * 340;
      int r = rem / 34;
      int col = rem - r * 34;
      int gh = h0 - 1 + r;
      int gw = w0 - 1 + col;
      int c = c0 + cc;
      float val = 0.f;
      if ((unsigned)gh < 128u && (unsigned)gw < 128u) {
        const float* sp = in0;
        int cl = c;
        if (CONCAT && c >= 64) { sp = in1; cl = c - 64; }
        val = sp[(((b << 6) + cl) << 14) + (gh << 7) + gw];
      }
      s_in[l] = val;
    }
    __syncthreads();
#pragma unroll
    for (int cc = 0; cc < CC; ++cc) {
      int base = cc * 340 + ty * 34 + tx;
      float vv[9];
      vv[0] = s_in[base];      vv[1] = s_in[base + 1];  vv[2] = s_in[base + 2];
      vv[3] = s_in[base + 34]; vv[4] = s_in[base + 35]; vv[5] = s_in[base + 36];
      vv[6] = s_in[base + 68]; vv[7] = s_in[base + 69]; vv[8] = s_in[base + 70];
      const float* wr = wT + (c0 + cc) * 576 + s * OCB;  // (c*9+k)*64
#pragma unroll
      for (int k = 0; k < 9; ++k) {
        const float* wk = wr + k * 64;
        float vk = vv[k];
#pragma unroll
        for (int oc = 0; oc < OCB; ++oc)
          acc[oc] = fmaf(vk, wk[oc], acc[oc]);   // wk[oc] wave-uniform -> s_load
      }
    }
  }
#pragma unroll
  for (int oc = 0; oc < OCB; ++oc) {
    int o = s * OCB + oc;
    float v = acc[oc] + bias[o];
    v = (v >= 0.f) ? v : 0.1f * v;
    out[(((b << 6) + o) << 14) + (h << 7) + w] = v;
  }
}

// ---------------- offset/mask conv: 64 -> 27 ch, fused 15*tanh / sigmoid.
// wT layout [c][k][27].
__global__ __launch_bounds__(256) void conv_off_kernel(
    const float* __restrict__ in0, const float* __restrict__ wT,
    const float* __restrict__ bias, float* __restrict__ off_out,
    float* __restrict__ mask_out) {
  constexpr int CC = 4;
  __shared__ float s_in[CC * 340];
  int tid = threadIdx.x;
  int tx = tid & 31, ty = tid >> 5;
  int w0 = blockIdx.x * 32, h0 = blockIdx.y * 8;
  int b = blockIdx.z;
  int h = h0 + ty, w = w0 + tx;

  float acc[27];
#pragma unroll
  for (int i = 0; i < 27; ++i) acc[i] = 0.f;

  for (int c0 = 0; c0 < 64; c0 += CC) {
    __syncthreads();
    for (int l = tid; l < CC * 340; l += 256) {
      int cc = l / 340;
      int rem = l - cc * 340;
      int r = rem / 34;
      int col = rem - r * 34;
      int gh = h0 - 1 + r;
      int gw = w0 - 1 + col;
      int c = c0 + cc;
      float val = 0.f;
      if ((unsigned)gh < 128u && (unsigned)gw < 128u)
        val = in0[(((b << 6) + c) << 14) + (gh << 7) + gw];
      s_in[l] = val;
    }
    __syncthreads();
#pragma unroll
    for (int cc = 0; cc < CC; ++cc) {
      int base = cc * 340 + ty * 34 + tx;
      float vv[9];
      vv[0] = s_in[base];      vv[1] = s_in[base + 1];  vv[2] = s_in[base + 2];
      vv[3] = s_in[base + 34]; vv[4] = s_in[base + 35]; vv[5] = s_in[base + 36];
      vv[6] = s_in[base + 68]; vv[7] = s_in[base + 69]; vv[8] = s_in[base + 70];
      const float* wr = wT + (c0 + cc) * 243;  // (c*9+k)*27
#pragma unroll
      for (int k = 0; k < 9; ++k) {
        const float* wk = wr + k * 27;
        float vk = vv[k];
#pragma unroll
        for (int oc = 0; oc < 27; ++oc)
          acc[oc] = fmaf(vk, wk[oc], acc[oc]);
      }
    }
  }
  int hw = (h << 7) + w;
#pragma unroll
  for (int oc = 0; oc < 27; ++oc) {
    float v = acc[oc] + bias[oc];
    if (oc < 18) {
      off_out[((b * 18 + oc) << 14) + hw] = 15.f * tanhf(v);
    } else {
      mask_out[((b * 9 + (oc - 18)) << 14) + hw] = 1.f / (1.f + expf(-v));
    }
  }
}

// ---------------- modulated deformable conv + bias + lrelu.
// xT is NHWC (B,128,128,64); wT layout [c][k][64] -> element (c*9+k)*64+oc.
__global__ __launch_bounds__(256) void dcn_lrelu_kernel(
    const float* __restrict__ xT, const float* __restrict__ off,
    const float* __restrict__ msk, const float* __restrict__ wT,
    const float* __restrict__ bias, float* __restrict__ out) {
  int tid = threadIdx.x;
  int tx = tid & 31, ty = tid >> 5;
  int w = blockIdx.x * 32 + tx;
  int h = blockIdx.y * 8 + ty;
  int b = blockIdx.z;
  int hw = (h << 7) + w;

  float acc[64];
#pragma unroll
  for (int i = 0; i < 64; ++i) acc[i] = 0.f;

#pragma unroll
  for (int k = 0; k < 9; ++k) {
    int kr = k / 3;
    int ki = kr - 1;
    int kj = k - kr * 3 - 1;
    float oy = off[((b * 18 + 2 * k) << 14) + hw];
    float ox = off[((b * 18 + 2 * k + 1) << 14) + hw];
    float m = msk[((b * 9 + k) << 14) + hw];
    float py = (float)(h + ki) + oy;
    float px = (float)(w + kj) + ox;
    float fy = floorf(py), fx = floorf(px);
    float wy = py - fy, wx = px - fx;
    int y0 = (int)fy, x0 = (int)fx;
    int y1 = y0 + 1, x1 = x0 + 1;
    float vy0 = ((unsigned)y0 < 128u) ? 1.f : 0.f;
    float vy1 = ((unsigned)y1 < 128u) ? 1.f : 0.f;
    float vx0 = ((unsigned)x0 < 128u) ? 1.f : 0.f;
    float vx1 = ((unsigned)x1 < 128u) ? 1.f : 0.f;
    float ey = 1.f - wy, ex = 1.f - wx;
    float w00 = ey * ex * m * vy0 * vx0;
    float w01 = ey * wx * m * vy0 * vx1;
    float w10 = wy * ex * m * vy1 * vx0;
    float w11 = wy * wx * m * vy1 * vx1;
    int y0c = min(max(y0, 0), 127), y1c = min(max(y1, 0), 127);
    int x0c = min(max(x0, 0), 127), x1c = min(max(x1, 0), 127);
    const float4* p00 = (const float4*)(xT + (size_t)((((b << 7) + y0c) << 7) + x0c) * 64);
    const float4* p01 = (const float4*)(xT + (size_t)((((b << 7) + y0c) << 7) + x1c) * 64);
    const float4* p10 = (const float4*)(xT + (size_t)((((b << 7) + y1c) << 7) + x0c) * 64);
    const float4* p11 = (const float4*)(xT + (size_t)((((b << 7) + y1c) << 7) + x1c) * 64);
    const float* wkb = wT + k * 64;
    for (int c4 = 0; c4 < 16; ++c4) {
      float4 a0 = p00[c4], a1 = p01[c4], a2 = p10[c4], a3 = p11[c4];
      float s0 = fmaf(w11, a3.x, fmaf(w10, a2.x, fmaf(w01, a1.x, w00 * a0.x)));
      float s1 = fmaf(w11, a3.y, fmaf(w10, a2.y, fmaf(w01, a1.y, w00 * a0.y)));
      float s2 = fmaf(w11, a3.z, fmaf(w10, a2.z, fmaf(w01, a1.z, w00 * a0.z)));
      float s3 = fmaf(w11, a3.w, fmaf(w10, a2.w, fmaf(w01, a1.w, w00 * a0.w)));
      const float* wk = wkb + c4 * 2304;  // c=4*c4, rows j at +576*j
#pragma unroll
      for (int oc = 0; oc < 64; ++oc) {
        float t = fmaf(s0, wk[oc], acc[oc]);
        t = fmaf(s1, wk[576 + oc], t);
        t = fmaf(s2, wk[1152 + oc], t);
        acc[oc] = fmaf(s3, wk[1728 + oc], t);
      }
    }
  }
#pragma unroll
  for (int oc = 0; oc < 64; ++oc) {
    float v = acc[oc] + bias[oc];
    v = (v >= 0.f) ? v : 0.1f * v;
    out[(((b << 6) + oc) << 14) + hw] = v;
  }
}

extern "C" void kernel_launch(void* const* d_in, const int* in_sizes, int n_in,
                              void* d_out, int out_size, void* d_ws, size_t ws_size,
                              hipStream_t stream) {
  const float* nbr   = (const float*)d_in[0];
  const float* refp  = (const float*)d_in[1];
  const float* w1    = (const float*)d_in[2];
  const float* b1    = (const float*)d_in[3];
  const float* w2    = (const float*)d_in[4];
  const float* b2    = (const float*)d_in[5];
  const float* w3    = (const float*)d_in[6];
  const float* b3    = (const float*)d_in[7];
  const float* w_off = (const float*)d_in[8];
  const float* b_off = (const float*)d_in[9];
  const float* w_dcn = (const float*)d_in[10];
  const float* b_dcn = (const float*)d_in[11];

  float* outp = (float*)d_out;
  float* feat = outp;                       // 4*64*16384 = 4194304
  float* offp = outp + 4194304;             // 4*18*16384 = 1179648
  float* mskp = outp + 4194304 + 1179648;   // 4*9*16384  = 589824

  char* ws = (char*)d_ws;
  float* buf0  = (float*)ws;                          // 16 MB ping buffer
  float* wT1   = (float*)(ws + (size_t)(16u << 20));  // 73728 floats
  float* wT2   = wT1 + 73728;                         // 36864
  float* wT3   = wT2 + 36864;                         // 36864
  float* wToff = wT3 + 36864;                         // 15552
  float* wTdcn = wToff + 15552;                       // 36864

  wtrans_kernel<<<dim3((73728 + 255) / 256), 256, 0, stream>>>(w1, wT1, 64, 128);
  wtrans_kernel<<<dim3((36864 + 255) / 256), 256, 0, stream>>>(w2, wT2, 64, 64);
  wtrans_kernel<<<dim3((36864 + 255) / 256), 256, 0, stream>>>(w3, wT3, 64, 64);
  wtrans_kernel<<<dim3((15552 + 255) / 256), 256, 0, stream>>>(w_off, wToff, 27, 64);
  wtrans_kernel<<<dim3((36864 + 255) / 256), 256, 0, stream>>>(w_dcn, wTdcn, 64, 64);

  // conv1: concat(nbr,ref) 128ch -> 64ch, lrelu, into buf0
  conv3x3_lrelu_kernel<128, true, 2><<<dim3(4, 16, 8), 256, 0, stream>>>(nbr, refp, wT1, b1, buf0);
  // conv2: buf0 -> feat region (used as pong; overwritten later by DCN)
  conv3x3_lrelu_kernel<64, false, 2><<<dim3(4, 16, 8), 256, 0, stream>>>(buf0, nullptr, wT2, b2, feat);
  // conv3: feat -> buf0
  conv3x3_lrelu_kernel<64, false, 2><<<dim3(4, 16, 8), 256, 0, stream>>>(feat, nullptr, wT3, b3, buf0);
  // conv_off: buf0 -> offset/mask output regions (fused 15*tanh / sigmoid)
  conv_off_kernel<<<dim3(4, 16, 4), 256, 0, stream>>>(buf0, wToff, b_off, offp, mskp);
  // transpose nbr -> NHWC into buf0 (conv outputs no longer needed there)
  transpose_nhwc_kernel<<<dim3(512), 256, 0, stream>>>(nbr, buf0);
  // DCN: sample buf0 (NHWC) at offsets, modulate, matmul, +bias, lrelu -> feat
  dcn_lrelu_kernel<<<dim3(4, 16, 4), 256, 0, stream>>>(buf0, offp, mskp, wTdcn, b_dcn, feat);
}